// Round 1
// baseline (439.942 us; speedup 1.0000x reference)
//
#include <hip/hip_runtime.h>
#include <stdint.h>

typedef __attribute__((ext_vector_type(8))) short short8;
typedef __attribute__((ext_vector_type(4))) short short4v;
typedef __attribute__((ext_vector_type(4))) float float4v;

#define DEV __device__ __forceinline__

DEV ushort f2bf(float f){
  uint32_t u = __float_as_uint(f);
  u = (u + 0x7fffu + ((u >> 16) & 1u)) >> 16;
  return (ushort)u;
}
DEV float bf2f(ushort h){
  uint32_t u = ((uint32_t)h) << 16;
  return __uint_as_float(u);
}

DEV void gload16(const void* g, void* l){
  __builtin_amdgcn_global_load_lds((const __attribute__((address_space(1))) void*)g,
                                   (__attribute__((address_space(3))) void*)l, 16, 0, 0);
}

// ---------------- RoPE cos/sin table: [2048][32] each ----------------
__global__ __launch_bounds__(256) void k_rope_table(float* __restrict__ cost, float* __restrict__ sint){
  int i = blockIdx.x * 256 + threadIdx.x;          // 65536
  int s = i >> 5, d = i & 31;
  float inv = powf(10000.0f, -(float)d / 32.0f);
  float ang = (float)s * inv;
  float sv, cv;
  sincosf(ang, &sv, &cv);
  cost[i] = cv;
  sint[i] = sv;
}

// ---------------- cast x f32 -> bf16 ----------------
__global__ __launch_bounds__(256) void k_cast_x(const float* __restrict__ src, ushort* __restrict__ dst){
  int i = blockIdx.x * 256 + threadIdx.x;          // 2097152 threads, 4 elems each
  float4v v = *(const float4v*)(src + (size_t)i * 4);
  short4v o;
  o[0] = (short)f2bf(v[0]); o[1] = (short)f2bf(v[1]);
  o[2] = (short)f2bf(v[2]); o[3] = (short)f2bf(v[3]);
  *(short4v*)(dst + (size_t)i * 4) = o;
}

// ---------------- transpose + cast: src f32 [K][N] -> dst bf16 [N][K] ----------------
__global__ __launch_bounds__(256) void k_transpose_cast(const float* __restrict__ src, ushort* __restrict__ dst,
                                                        int N, int K){
  __shared__ float tile[32][33];
  int c0 = blockIdx.x * 32, r0 = blockIdx.y * 32;
  int tx = threadIdx.x & 31, ty = threadIdx.x >> 5;   // ty 0..7
  #pragma unroll
  for (int i = 0; i < 32; i += 8)
    tile[ty + i][tx] = src[(size_t)(r0 + ty + i) * N + (c0 + tx)];
  __syncthreads();
  #pragma unroll
  for (int i = 0; i < 32; i += 8)
    dst[(size_t)(c0 + ty + i) * K + (r0 + tx)] = f2bf(tile[tx][ty + i]);
}

// ---------------- GEMM: C[M][N] = A[M][K] * Bt[N][K]^T, bf16 in, bf16/f32 out ----------------
// m97 structure: 128x128 tile, BK=32, 4 waves (2x2), global_load_lds staging.
template<bool OUTF32>
__global__ __launch_bounds__(256) void k_gemm_bt(const ushort* __restrict__ A, const ushort* __restrict__ Bt,
                                                 void* __restrict__ Cp, int M, int N, int K, int nbx){
  __shared__ ushort As[128 * 32];
  __shared__ ushort Bs[128 * 32];
  int wg = blockIdx.x;
  int cpx = (int)gridDim.x >> 3;                 // grid divisible by 8
  wg = (wg & 7) * cpx + (wg >> 3);               // XCD swizzle
  int bn = wg % nbx, bm = wg / nbx;
  const int tid = threadIdx.x;
  const int w = tid >> 6, l = tid & 63, l15 = l & 15, hi = l >> 4;
  const int wr = w >> 1, wc = w & 1;
  float4v acc[4][4];
  #pragma unroll
  for (int a = 0; a < 4; ++a)
    #pragma unroll
    for (int b = 0; b < 4; ++b)
      acc[a][b] = (float4v){0.f, 0.f, 0.f, 0.f};
  const int nk = K >> 5;
  const size_t arow0 = (size_t)(bm * 128) * K;
  const size_t brow0 = (size_t)(bn * 128) * K;
  for (int kt = 0; kt < nk; ++kt){
    __syncthreads();
    #pragma unroll
    for (int r = 0; r < 2; ++r){
      int li = r * 256 + tid;                    // 0..511
      int row = li >> 2, col8 = (li & 3) * 8;
      gload16(A + arow0 + (size_t)row * K + kt * 32 + col8, (char*)As + li * 16);
      gload16(Bt + brow0 + (size_t)row * K + kt * 32 + col8, (char*)Bs + li * 16);
    }
    __syncthreads();
    short8 af[4], bfr[4];
    #pragma unroll
    for (int mf = 0; mf < 4; ++mf)
      af[mf] = *(const short8*)((const char*)As + (wr * 64 + mf * 16 + l15) * 64 + hi * 16);
    #pragma unroll
    for (int nf = 0; nf < 4; ++nf)
      bfr[nf] = *(const short8*)((const char*)Bs + (wc * 64 + nf * 16 + l15) * 64 + hi * 16);
    #pragma unroll
    for (int mf = 0; mf < 4; ++mf)
      #pragma unroll
      for (int nf = 0; nf < 4; ++nf)
        acc[mf][nf] = __builtin_amdgcn_mfma_f32_16x16x32_bf16(af[mf], bfr[nf], acc[mf][nf], 0, 0, 0);
  }
  #pragma unroll
  for (int mf = 0; mf < 4; ++mf){
    int row0 = bm * 128 + wr * 64 + mf * 16 + hi * 4;
    #pragma unroll
    for (int nf = 0; nf < 4; ++nf){
      int col = bn * 128 + wc * 64 + nf * 16 + l15;
      #pragma unroll
      for (int reg = 0; reg < 4; ++reg){
        size_t idx = (size_t)(row0 + reg) * N + col;
        if constexpr (OUTF32) ((float*)Cp)[idx] = acc[mf][nf][reg];
        else                  ((ushort*)Cp)[idx] = f2bf(acc[mf][nf][reg]);
      }
    }
  }
}

// ---------------- RoPE in-place on qkv (q cols [0,2048), k cols [2048,2560)) ----------------
__global__ __launch_bounds__(256) void k_rope(ushort* __restrict__ qkv, const float* __restrict__ cost,
                                              const float* __restrict__ sint){
  int t = blockIdx.x * 256 + threadIdx.x;        // 4096 * 320 = 1310720
  int row = t / 320;
  int rem = t - row * 320;
  int head = rem >> 3, d0 = (rem & 7) * 4;       // head 0..39 covers q(0..31) + k(32..39)
  int s = row & 2047;
  ushort* p = qkv + (size_t)row * 3072 + head * 64 + d0;
  short4v a = *(short4v*)p;
  short4v b = *(short4v*)(p + 32);
  float4v c  = *(const float4v*)(cost + s * 32 + d0);
  float4v sn = *(const float4v*)(sint + s * 32 + d0);
  short4v na, nb;
  #pragma unroll
  for (int j = 0; j < 4; ++j){
    float x1 = bf2f((ushort)a[j]), x2 = bf2f((ushort)b[j]);
    na[j] = (short)f2bf(x1 * c[j] - x2 * sn[j]);
    nb[j] = (short)f2bf(x2 * c[j] + x1 * sn[j]);
  }
  *(short4v*)p = na;
  *(short4v*)(p + 32) = nb;
}

// ---------------- causal GQA flash attention ----------------
// One wg per (b, h, 64-row q-tile). 4 waves; wave w owns q rows w*16..w*16+15.
// KV tiles of 64. K staged XOR-swizzled; V staged transposed+swizzled; P via per-wave LDS.
__global__ __launch_bounds__(256) void k_attn(const ushort* __restrict__ qkv, ushort* __restrict__ att){
  __shared__ ushort K_lds[64 * 64];
  __shared__ ushort Vt_lds[64 * 64];
  __shared__ ushort P_lds[4][16 * 64];
  int bx = blockIdx.x;
  bx = (bx & 7) * 256 + (bx >> 3);               // XCD swizzle (2048 blocks)
  const int qt = bx & 31;
  const int bh = bx >> 5;
  const int h = bh & 31, b = bh >> 5;
  const int hk = h >> 2;
  const int tid = threadIdx.x;
  const int w = tid >> 6, l = tid & 63, l15 = l & 15, hi = l >> 4;
  const int rb = b * 2048 + qt * 64;

  short8 qf[2];
  {
    const ushort* qrow = qkv + (size_t)(rb + w * 16 + l15) * 3072 + h * 64;
    qf[0] = *(const short8*)(qrow + hi * 8);
    qf[1] = *(const short8*)(qrow + 32 + hi * 8);
  }
  float4v o[4];
  #pragma unroll
  for (int nf = 0; nf < 4; ++nf) o[nf] = (float4v){0.f, 0.f, 0.f, 0.f};
  float m_run[4], l_run[4];
  #pragma unroll
  for (int r = 0; r < 4; ++r){ m_run[r] = -3e38f; l_run[r] = 0.f; }

  const ushort* kbase0 = qkv + (size_t)(b * 2048) * 3072 + 2048 + hk * 64;
  const ushort* vbase0 = qkv + (size_t)(b * 2048) * 3072 + 2560 + hk * 64;

  for (int t = 0; t <= qt; ++t){
    __syncthreads();
    {
      const ushort* kb = kbase0 + (size_t)t * 64 * 3072;
      const ushort* vb = vbase0 + (size_t)t * 64 * 3072;
      #pragma unroll
      for (int c = 0; c < 2; ++c){
        int li = c * 256 + tid;                  // 0..511
        int r = li >> 3, col8 = (li & 7) * 8;
        short8 kv = *(const short8*)(kb + (size_t)r * 3072 + col8);
        *(short8*)((char*)K_lds + r * 128 + ((col8 * 2) ^ ((r & 7) << 4))) = kv;
        short8 vv = *(const short8*)(vb + (size_t)r * 3072 + col8);
        #pragma unroll
        for (int j = 0; j < 8; ++j){
          int d = col8 + j;
          *((ushort*)((char*)Vt_lds + d * 128 + ((r * 2) ^ ((d & 7) << 4)))) = (ushort)vv[j];
        }
      }
    }
    __syncthreads();

    // QK^T: S[16 q][64 k]
    float4v s[4];
    #pragma unroll
    for (int nf = 0; nf < 4; ++nf) s[nf] = (float4v){0.f, 0.f, 0.f, 0.f};
    #pragma unroll
    for (int nf = 0; nf < 4; ++nf){
      int krow = l15 + nf * 16;
      #pragma unroll
      for (int kk = 0; kk < 2; ++kk){
        short8 kf = *(const short8*)((const char*)K_lds + krow * 128 + ((kk * 64 + hi * 16) ^ ((krow & 7) << 4)));
        s[nf] = __builtin_amdgcn_mfma_f32_16x16x32_bf16(qf[kk], kf, s[nf], 0, 0, 0);
      }
    }

    // online softmax (rows = hi*4+reg, cols = l15+nf*16)
    const int q0 = qt * 64 + w * 16 + hi * 4;
    const int k0 = t * 64 + l15;
    float p[4][4];                                // [nf][reg]
    #pragma unroll
    for (int reg = 0; reg < 4; ++reg){
      float sv0 = s[0][reg] * 0.125f, sv1 = s[1][reg] * 0.125f;
      float sv2 = s[2][reg] * 0.125f, sv3 = s[3][reg] * 0.125f;
      if (t == qt){
        int qg = q0 + reg;
        if (k0      > qg) sv0 = -3e38f;
        if (k0 + 16 > qg) sv1 = -3e38f;
        if (k0 + 32 > qg) sv2 = -3e38f;
        if (k0 + 48 > qg) sv3 = -3e38f;
      }
      float mt = fmaxf(fmaxf(sv0, sv1), fmaxf(sv2, sv3));
      #pragma unroll
      for (int msk = 1; msk < 16; msk <<= 1) mt = fmaxf(mt, __shfl_xor(mt, msk, 64));
      float mnew = fmaxf(m_run[reg], mt);
      float corr = __expf(m_run[reg] - mnew);
      m_run[reg] = mnew;
      float p0 = __expf(sv0 - mnew), p1 = __expf(sv1 - mnew);
      float p2 = __expf(sv2 - mnew), p3 = __expf(sv3 - mnew);
      p[0][reg] = p0; p[1][reg] = p1; p[2][reg] = p2; p[3][reg] = p3;
      float ls = p0 + p1 + p2 + p3;
      #pragma unroll
      for (int msk = 1; msk < 16; msk <<= 1) ls += __shfl_xor(ls, msk, 64);
      l_run[reg] = l_run[reg] * corr + ls;
      o[0][reg] *= corr; o[1][reg] *= corr; o[2][reg] *= corr; o[3][reg] *= corr;
    }

    // P -> LDS (bf16, swizzled), per-wave private region: no barrier needed
    #pragma unroll
    for (int nf = 0; nf < 4; ++nf)
      #pragma unroll
      for (int reg = 0; reg < 4; ++reg){
        int row = hi * 4 + reg;
        int c2 = (l15 + nf * 16) * 2;
        *((ushort*)((char*)P_lds[w] + row * 128 + (c2 ^ ((row & 7) << 4)))) = f2bf(p[nf][reg]);
      }

    // PV: O[16 q][64 d] += P[16][64] * V[64][64]
    short8 pa[2];
    #pragma unroll
    for (int kk = 0; kk < 2; ++kk)
      pa[kk] = *(const short8*)((const char*)P_lds[w] + l15 * 128 + ((kk * 64 + hi * 16) ^ ((l15 & 7) << 4)));
    #pragma unroll
    for (int nf = 0; nf < 4; ++nf){
      int vrow = l15 + nf * 16;
      #pragma unroll
      for (int kk = 0; kk < 2; ++kk){
        short8 vf = *(const short8*)((const char*)Vt_lds + vrow * 128 + ((kk * 64 + hi * 16) ^ ((vrow & 7) << 4)));
        o[nf] = __builtin_amdgcn_mfma_f32_16x16x32_bf16(pa[kk], vf, o[nf], 0, 0, 0);
      }
    }
  }

  // epilogue: O / l -> att bf16 [4096][2048] (token-major, head cols)
  ushort* ob = att + (size_t)(rb + w * 16) * 2048 + h * 64;
  #pragma unroll
  for (int reg = 0; reg < 4; ++reg){
    float invl = 1.0f / l_run[reg];
    int row = hi * 4 + reg;
    #pragma unroll
    for (int nf = 0; nf < 4; ++nf)
      ob[(size_t)row * 2048 + nf * 16 + l15] = f2bf(o[nf][reg] * invl);
  }
}

// ---------------- launch ----------------
extern "C" void kernel_launch(void* const* d_in, const int* in_sizes, int n_in,
                              void* d_out, int out_size, void* d_ws, size_t ws_size,
                              hipStream_t stream) {
  const float* x  = (const float*)d_in[0];
  // d_in[1] = mask (causal tril; handled analytically)
  const float* Wq = (const float*)d_in[2];
  const float* Wk = (const float*)d_in[3];
  const float* Wv = (const float*)d_in[4];
  const float* Wo = (const float*)d_in[5];

  char* ws = (char*)d_ws;
  ushort* xb    = (ushort*)(ws);                       // [4096][2048] bf16    16.0 MiB
  ushort* wqkvt = (ushort*)(ws + 16777216);            // [3072][2048] bf16    12.0 MiB
  ushort* wot   = (ushort*)(ws + 29360128);            // [2048][2048] bf16     8.0 MiB
  ushort* qkv   = (ushort*)(ws + 37748736);            // [4096][3072] bf16    24.0 MiB
  ushort* att   = (ushort*)(ws + 62914560);            // [4096][2048] bf16    16.0 MiB
  float*  cost  = (float*)(ws + 79691776);             // [2048][32] f32
  float*  sint  = (float*)(ws + 79953920);             // [2048][32] f32

  k_rope_table<<<256, 256, 0, stream>>>(cost, sint);
  k_cast_x<<<8192, 256, 0, stream>>>(x, xb);
  k_transpose_cast<<<dim3(64, 64), 256, 0, stream>>>(Wq, wqkvt, 2048, 2048);
  k_transpose_cast<<<dim3(16, 64), 256, 0, stream>>>(Wk, wqkvt + (size_t)2048 * 2048, 512, 2048);
  k_transpose_cast<<<dim3(16, 64), 256, 0, stream>>>(Wv, wqkvt + (size_t)2560 * 2048, 512, 2048);
  k_transpose_cast<<<dim3(64, 64), 256, 0, stream>>>(Wo, wot, 2048, 2048);
  k_gemm_bt<false><<<768, 256, 0, stream>>>(xb, wqkvt, qkv, 4096, 3072, 2048, 24);
  k_rope<<<5120, 256, 0, stream>>>(qkv, cost, sint);
  k_attn<<<2048, 256, 0, stream>>>(qkv, att);
  k_gemm_bt<true><<<512, 256, 0, stream>>>(att, wot, d_out, 4096, 2048, 2048, 16);
}

// Round 2
// 274.857 us; speedup vs baseline: 1.6006x; 1.6006x over previous
//
#include <hip/hip_runtime.h>
#include <stdint.h>

typedef __attribute__((ext_vector_type(8))) short short8;
typedef __attribute__((ext_vector_type(4))) short short4v;
typedef __attribute__((ext_vector_type(4))) float float4v;

#define DEV __device__ __forceinline__

DEV ushort f2bf(float f){
  uint32_t u = __float_as_uint(f);
  u = (u + 0x7fffu + ((u >> 16) & 1u)) >> 16;
  return (ushort)u;
}
DEV float bf2f(ushort h){
  uint32_t u = ((uint32_t)h) << 16;
  return __uint_as_float(u);
}

DEV void gload16(const void* g, void* l){
  __builtin_amdgcn_global_load_lds((const __attribute__((address_space(1))) void*)g,
                                   (__attribute__((address_space(3))) void*)l, 16, 0, 0);
}

// ---------------- RoPE cos/sin table: [2048][32] each ----------------
__global__ __launch_bounds__(256) void k_rope_table(float* __restrict__ cost, float* __restrict__ sint){
  int i = blockIdx.x * 256 + threadIdx.x;          // 65536
  int s = i >> 5, d = i & 31;
  float inv = powf(10000.0f, -(float)d / 32.0f);
  float ang = (float)s * inv;
  float sv, cv;
  sincosf(ang, &sv, &cv);
  cost[i] = cv;
  sint[i] = sv;
}

// ---------------- cast x f32 -> bf16 ----------------
__global__ __launch_bounds__(256) void k_cast_x(const float* __restrict__ src, ushort* __restrict__ dst){
  int i = blockIdx.x * 256 + threadIdx.x;          // 2097152 threads, 4 elems each
  float4v v = *(const float4v*)(src + (size_t)i * 4);
  short4v o;
  o[0] = (short)f2bf(v[0]); o[1] = (short)f2bf(v[1]);
  o[2] = (short)f2bf(v[2]); o[3] = (short)f2bf(v[3]);
  *(short4v*)(dst + (size_t)i * 4) = o;
}

// ---------------- transpose + cast + scale: src f32 [K][N] -> dst bf16 [N][K] ----------------
__global__ __launch_bounds__(256) void k_transpose_cast(const float* __restrict__ src, ushort* __restrict__ dst,
                                                        int N, int K, float scale){
  __shared__ float tile[32][33];
  int c0 = blockIdx.x * 32, r0 = blockIdx.y * 32;
  int tx = threadIdx.x & 31, ty = threadIdx.x >> 5;   // ty 0..7
  #pragma unroll
  for (int i = 0; i < 32; i += 8)
    tile[ty + i][tx] = src[(size_t)(r0 + ty + i) * N + (c0 + tx)];
  __syncthreads();
  #pragma unroll
  for (int i = 0; i < 32; i += 8)
    dst[(size_t)(c0 + ty + i) * K + (r0 + tx)] = f2bf(tile[tx][ty + i] * scale);
}

// ---------------- GEMM: C[M][N] = A[M][K] * Bt[N][K]^T, bf16 in, bf16/f32 out ----------------
template<bool OUTF32>
__global__ __launch_bounds__(256) void k_gemm_bt(const ushort* __restrict__ A, const ushort* __restrict__ Bt,
                                                 void* __restrict__ Cp, int M, int N, int K, int nbx){
  __shared__ ushort As[128 * 32];
  __shared__ ushort Bs[128 * 32];
  int wg = blockIdx.x;
  int cpx = (int)gridDim.x >> 3;                 // grid divisible by 8
  wg = (wg & 7) * cpx + (wg >> 3);               // XCD swizzle
  int bn = wg % nbx, bm = wg / nbx;
  const int tid = threadIdx.x;
  const int w = tid >> 6, l = tid & 63, l15 = l & 15, hi = l >> 4;
  const int wr = w >> 1, wc = w & 1;
  float4v acc[4][4];
  #pragma unroll
  for (int a = 0; a < 4; ++a)
    #pragma unroll
    for (int b = 0; b < 4; ++b)
      acc[a][b] = (float4v){0.f, 0.f, 0.f, 0.f};
  const int nk = K >> 5;
  const size_t arow0 = (size_t)(bm * 128) * K;
  const size_t brow0 = (size_t)(bn * 128) * K;
  for (int kt = 0; kt < nk; ++kt){
    __syncthreads();
    #pragma unroll
    for (int r = 0; r < 2; ++r){
      int li = r * 256 + tid;                    // 0..511
      int row = li >> 2, col8 = (li & 3) * 8;
      gload16(A + arow0 + (size_t)row * K + kt * 32 + col8, (char*)As + li * 16);
      gload16(Bt + brow0 + (size_t)row * K + kt * 32 + col8, (char*)Bs + li * 16);
    }
    __syncthreads();
    short8 af[4], bfr[4];
    #pragma unroll
    for (int mf = 0; mf < 4; ++mf)
      af[mf] = *(const short8*)((const char*)As + (wr * 64 + mf * 16 + l15) * 64 + hi * 16);
    #pragma unroll
    for (int nf = 0; nf < 4; ++nf)
      bfr[nf] = *(const short8*)((const char*)Bs + (wc * 64 + nf * 16 + l15) * 64 + hi * 16);
    #pragma unroll
    for (int mf = 0; mf < 4; ++mf)
      #pragma unroll
      for (int nf = 0; nf < 4; ++nf)
        acc[mf][nf] = __builtin_amdgcn_mfma_f32_16x16x32_bf16(af[mf], bfr[nf], acc[mf][nf], 0, 0, 0);
  }
  #pragma unroll
  for (int mf = 0; mf < 4; ++mf){
    int row0 = bm * 128 + wr * 64 + mf * 16 + hi * 4;
    #pragma unroll
    for (int nf = 0; nf < 4; ++nf){
      int col = bn * 128 + wc * 64 + nf * 16 + l15;
      #pragma unroll
      for (int reg = 0; reg < 4; ++reg){
        size_t idx = (size_t)(row0 + reg) * N + col;
        if constexpr (OUTF32) ((float*)Cp)[idx] = acc[mf][nf][reg];
        else                  ((ushort*)Cp)[idx] = f2bf(acc[mf][nf][reg]);
      }
    }
  }
}

// ---------------- RoPE in-place on qkv (q cols [0,2048), k cols [2048,2560)) ----------------
__global__ __launch_bounds__(256) void k_rope(ushort* __restrict__ qkv, const float* __restrict__ cost,
                                              const float* __restrict__ sint){
  int t = blockIdx.x * 256 + threadIdx.x;        // 4096 * 320 = 1310720
  int row = t / 320;
  int rem = t - row * 320;
  int head = rem >> 3, d0 = (rem & 7) * 4;       // head 0..39 covers q(0..31) + k(32..39)
  int s = row & 2047;
  ushort* p = qkv + (size_t)row * 3072 + head * 64 + d0;
  short4v a = *(short4v*)p;
  short4v b = *(short4v*)(p + 32);
  float4v c  = *(const float4v*)(cost + s * 32 + d0);
  float4v sn = *(const float4v*)(sint + s * 32 + d0);
  short4v na, nb;
  #pragma unroll
  for (int j = 0; j < 4; ++j){
    float x1 = bf2f((ushort)a[j]), x2 = bf2f((ushort)b[j]);
    na[j] = (short)f2bf(x1 * c[j] - x2 * sn[j]);
    nb[j] = (short)f2bf(x2 * c[j] + x1 * sn[j]);
  }
  *(short4v*)p = na;
  *(short4v*)(p + 32) = nb;
}

// ---------------- build Vt[b][hk][64 d][2048 s] from qkv v-cols ----------------
__global__ __launch_bounds__(256) void k_build_vt(const ushort* __restrict__ qkv, ushort* __restrict__ vt){
  __shared__ ushort tile[64][72];
  int g = blockIdx.x >> 5, st = blockIdx.x & 31;   // g = b*8+hk, st = s-tile
  int b = g >> 3, hk = g & 7;
  const ushort* src = qkv + (size_t)(b * 2048 + st * 64) * 3072 + 2560 + hk * 64;
  int tid = threadIdx.x;
  #pragma unroll
  for (int i = 0; i < 2; ++i){
    int r = i * 32 + (tid >> 3), c8 = (tid & 7) * 8;
    short8 v = *(const short8*)(src + (size_t)r * 3072 + c8);
    #pragma unroll
    for (int j = 0; j < 8; ++j) tile[r][c8 + j] = (ushort)v[j];
  }
  __syncthreads();
  ushort* dst = vt + (size_t)g * 64 * 2048 + st * 64;
  #pragma unroll
  for (int i = 0; i < 2; ++i){
    int d = i * 32 + (tid >> 3), s8 = (tid & 7) * 8;
    short8 ov;
    #pragma unroll
    for (int j = 0; j < 8; ++j) ov[j] = (short)tile[s8 + j][d];
    *(short8*)(dst + (size_t)d * 2048 + s8) = ov;
  }
}

// ---------------- causal GQA flash attention v2 ----------------
// 4 waves x 32 q rows = 128 q rows/block. KV tiles of 64, double-buffered LDS,
// async-stage split, swizzled K / Vt, heavy-first + XCD-grouped scheduling.
// Q pre-scaled by HD^-0.5*log2e (folded into Wq) -> softmax in base 2.
__global__ __launch_bounds__(256) void k_attn2(const ushort* __restrict__ qkv, const ushort* __restrict__ vt,
                                               ushort* __restrict__ att){
  __shared__ ushort K_lds[2][64 * 64];
  __shared__ ushort V_lds[2][64 * 64];
  __shared__ ushort P_lds[4][32 * 64];
  const int raw = blockIdx.x;                     // 1024
  const int xcd = raw & 7, slot = raw >> 3;       // slot 0..127
  const int qb = 15 - (slot >> 3);                // heavy tiles dispatch first
  const int rem = slot & 7;
  const int g = xcd * 2 + (rem >> 2);             // b*8+hk : 2 KV-groups per XCD
  const int b = g >> 3, hk = g & 7;
  const int h = hk * 4 + (rem & 3);
  const int tid = threadIdx.x;
  const int w = tid >> 6, l = tid & 63, l15 = l & 15, hi = l >> 4;
  const int q0 = qb * 128;
  const int qw = q0 + w * 32;                     // this wave's first q row

  // Q fragments: rows qw + mf*16 + l15, d = kk*32 + hi*8
  short8 qf[2][2];
  {
    const ushort* qbase = qkv + (size_t)(b * 2048 + qw) * 3072 + h * 64;
    #pragma unroll
    for (int mf = 0; mf < 2; ++mf)
      #pragma unroll
      for (int kk = 0; kk < 2; ++kk)
        qf[mf][kk] = *(const short8*)(qbase + (size_t)(mf * 16 + l15) * 3072 + kk * 32 + hi * 8);
  }

  float4v o[2][4];
  #pragma unroll
  for (int mf = 0; mf < 2; ++mf)
    #pragma unroll
    for (int nf = 0; nf < 4; ++nf) o[mf][nf] = (float4v){0.f, 0.f, 0.f, 0.f};
  float m_run[2][4], l_part[2][4];
  #pragma unroll
  for (int mf = 0; mf < 2; ++mf)
    #pragma unroll
    for (int r = 0; r < 4; ++r){ m_run[mf][r] = -3e38f; l_part[mf][r] = 0.f; }

  const ushort* kbase = qkv + (size_t)(b * 2048) * 3072 + 2048 + hk * 64;
  const ushort* vbase = vt + (size_t)g * 64 * 2048;
  const int nt = qb * 2 + 2;
  const int srow = tid >> 3, scol = (tid & 7) * 8;   // staging: rows srow, srow+32

  // prologue: stage tile 0 into buf 0
  {
    #pragma unroll
    for (int i = 0; i < 2; ++i){
      int r = i * 32 + srow;
      short8 kv = *(const short8*)(kbase + (size_t)r * 3072 + scol);
      short8 vv = *(const short8*)(vbase + (size_t)r * 2048 + scol);
      *(short8*)((char*)K_lds[0] + r * 128 + ((scol * 2) ^ ((r & 7) << 4))) = kv;
      *(short8*)((char*)V_lds[0] + r * 128 + ((scol * 2) ^ ((r & 7) << 4))) = vv;
    }
  }
  __syncthreads();

  int cur = 0;
  for (int t = 0; t < nt; ++t){
    // issue next-tile loads early (hide HBM/L2 latency under compute)
    short8 kpre[2], vpre[2];
    const bool more = (t + 1 < nt);
    if (more){
      const ushort* kb = kbase + (size_t)(t + 1) * 64 * 3072;
      const ushort* vb = vbase + (t + 1) * 64;
      #pragma unroll
      for (int i = 0; i < 2; ++i){
        int r = i * 32 + srow;
        kpre[i] = *(const short8*)(kb + (size_t)r * 3072 + scol);
        vpre[i] = *(const short8*)(vb + (size_t)r * 2048 + scol);
      }
    }

    const bool active = (t * 64 <= qw + 31);
    if (active){
      // ---- QK^T ----
      float4v s[2][4];
      #pragma unroll
      for (int mf = 0; mf < 2; ++mf)
        #pragma unroll
        for (int nf = 0; nf < 4; ++nf) s[mf][nf] = (float4v){0.f, 0.f, 0.f, 0.f};
      __builtin_amdgcn_s_setprio(1);
      #pragma unroll
      for (int nf = 0; nf < 4; ++nf){
        int krow = nf * 16 + l15;
        #pragma unroll
        for (int kk = 0; kk < 2; ++kk){
          short8 kf = *(const short8*)((const char*)K_lds[cur] + krow * 128 + ((kk * 64 + hi * 16) ^ ((krow & 7) << 4)));
          s[0][nf] = __builtin_amdgcn_mfma_f32_16x16x32_bf16(qf[0][kk], kf, s[0][nf], 0, 0, 0);
          s[1][nf] = __builtin_amdgcn_mfma_f32_16x16x32_bf16(qf[1][kk], kf, s[1][nf], 0, 0, 0);
        }
      }
      __builtin_amdgcn_s_setprio(0);

      // ---- online softmax (base 2; scale folded into Wq) ----
      #pragma unroll
      for (int mf = 0; mf < 2; ++mf){
        const bool domask = (t * 64 + 63 > qw + mf * 16 + 15) || (t * 64 + 63 > qw + mf * 16);
        #pragma unroll
        for (int reg = 0; reg < 4; ++reg){
          float s0 = s[mf][0][reg], s1 = s[mf][1][reg];
          float s2 = s[mf][2][reg], s3 = s[mf][3][reg];
          if (domask){
            int qg = qw + mf * 16 + hi * 4 + reg;
            int k0 = t * 64 + l15;
            if (k0      > qg) s0 = -3e38f;
            if (k0 + 16 > qg) s1 = -3e38f;
            if (k0 + 32 > qg) s2 = -3e38f;
            if (k0 + 48 > qg) s3 = -3e38f;
          }
          float mt = fmaxf(fmaxf(s0, s1), fmaxf(s2, s3));
          #pragma unroll
          for (int msk = 1; msk < 16; msk <<= 1) mt = fmaxf(mt, __shfl_xor(mt, msk, 64));
          float mn = fmaxf(m_run[mf][reg], mt);
          float corr = __builtin_amdgcn_exp2f(m_run[mf][reg] - mn);
          m_run[mf][reg] = mn;
          float p0 = __builtin_amdgcn_exp2f(s0 - mn), p1 = __builtin_amdgcn_exp2f(s1 - mn);
          float p2 = __builtin_amdgcn_exp2f(s2 - mn), p3 = __builtin_amdgcn_exp2f(s3 - mn);
          l_part[mf][reg] = l_part[mf][reg] * corr + (p0 + p1 + p2 + p3);
          o[mf][0][reg] *= corr; o[mf][1][reg] *= corr;
          o[mf][2][reg] *= corr; o[mf][3][reg] *= corr;
          int row = mf * 16 + hi * 4 + reg;
          char* pb = (char*)P_lds[w] + row * 128;
          int sw = (row & 7) << 4;
          *((ushort*)(pb + (((l15      ) * 2) ^ sw))) = f2bf(p0);
          *((ushort*)(pb + (((l15 + 16) * 2) ^ sw))) = f2bf(p1);
          *((ushort*)(pb + (((l15 + 32) * 2) ^ sw))) = f2bf(p2);
          *((ushort*)(pb + (((l15 + 48) * 2) ^ sw))) = f2bf(p3);
        }
      }

      // ---- PV ----
      __builtin_amdgcn_s_setprio(1);
      #pragma unroll
      for (int mf = 0; mf < 2; ++mf){
        int prow = mf * 16 + l15;
        short8 pa[2];
        #pragma unroll
        for (int kk = 0; kk < 2; ++kk)
          pa[kk] = *(const short8*)((const char*)P_lds[w] + prow * 128 + ((kk * 64 + hi * 16) ^ ((prow & 7) << 4)));
        #pragma unroll
        for (int nf = 0; nf < 4; ++nf){
          int vrow = nf * 16 + l15;
          #pragma unroll
          for (int kk = 0; kk < 2; ++kk){
            short8 vf = *(const short8*)((const char*)V_lds[cur] + vrow * 128 + ((kk * 64 + hi * 16) ^ ((vrow & 7) << 4)));
            o[mf][nf] = __builtin_amdgcn_mfma_f32_16x16x32_bf16(pa[kk], vf, o[mf][nf], 0, 0, 0);
          }
        }
      }
      __builtin_amdgcn_s_setprio(0);
    }

    if (more){
      int nxt = cur ^ 1;
      #pragma unroll
      for (int i = 0; i < 2; ++i){
        int r = i * 32 + srow;
        *(short8*)((char*)K_lds[nxt] + r * 128 + ((scol * 2) ^ ((r & 7) << 4))) = kpre[i];
        *(short8*)((char*)V_lds[nxt] + r * 128 + ((scol * 2) ^ ((r & 7) << 4))) = vpre[i];
      }
      __syncthreads();
      cur = nxt;
    }
  }

  // ---- epilogue: reduce l across 16 lanes, normalize, store bf16 ----
  ushort* ob = att + (size_t)(b * 2048 + qw) * 2048 + h * 64;
  #pragma unroll
  for (int mf = 0; mf < 2; ++mf)
    #pragma unroll
    for (int reg = 0; reg < 4; ++reg){
      float ls = l_part[mf][reg];
      #pragma unroll
      for (int msk = 1; msk < 16; msk <<= 1) ls += __shfl_xor(ls, msk, 64);
      float invl = 1.0f / ls;
      int row = mf * 16 + hi * 4 + reg;
      #pragma unroll
      for (int nf = 0; nf < 4; ++nf)
        ob[(size_t)row * 2048 + nf * 16 + l15] = f2bf(o[mf][nf][reg] * invl);
    }
}

// ---------------- launch ----------------
extern "C" void kernel_launch(void* const* d_in, const int* in_sizes, int n_in,
                              void* d_out, int out_size, void* d_ws, size_t ws_size,
                              hipStream_t stream) {
  const float* x  = (const float*)d_in[0];
  // d_in[1] = mask (causal tril; handled analytically)
  const float* Wq = (const float*)d_in[2];
  const float* Wk = (const float*)d_in[3];
  const float* Wv = (const float*)d_in[4];
  const float* Wo = (const float*)d_in[5];

  char* ws = (char*)d_ws;
  ushort* xb    = (ushort*)(ws);                       // [4096][2048] bf16    16 MiB
  ushort* wqkvt = (ushort*)(ws + (16u << 20));         // [3072][2048] bf16    12 MiB
  ushort* wot   = (ushort*)(ws + (28u << 20));         // [2048][2048] bf16     8 MiB
  ushort* qkv   = (ushort*)(ws + (36u << 20));         // [4096][3072] bf16    24 MiB
  ushort* att   = (ushort*)(ws + (60u << 20));         // [4096][2048] bf16    16 MiB
  ushort* vt    = (ushort*)(ws + (76u << 20));         // [16][64][2048] bf16   4 MiB
  float*  cost  = (float*)(ws + (80u << 20));          // [2048][32] f32
  float*  sint  = (float*)(ws + (80u << 20) + 262144);

  const float qscale = 0.125f * 1.4426950408889634f;   // HD^-0.5 * log2(e), folded into Wq

  k_rope_table<<<256, 256, 0, stream>>>(cost, sint);
  k_cast_x<<<8192, 256, 0, stream>>>(x, xb);
  k_transpose_cast<<<dim3(64, 64), 256, 0, stream>>>(Wq, wqkvt, 2048, 2048, qscale);
  k_transpose_cast<<<dim3(16, 64), 256, 0, stream>>>(Wk, wqkvt + (size_t)2048 * 2048, 512, 2048, 1.0f);
  k_transpose_cast<<<dim3(16, 64), 256, 0, stream>>>(Wv, wqkvt + (size_t)2560 * 2048, 512, 2048, 1.0f);
  k_transpose_cast<<<dim3(64, 64), 256, 0, stream>>>(Wo, wot, 2048, 2048, 1.0f);
  k_gemm_bt<false><<<768, 256, 0, stream>>>(xb, wqkvt, qkv, 4096, 3072, 2048, 24);
  k_rope<<<5120, 256, 0, stream>>>(qkv, cost, sint);
  k_build_vt<<<512, 256, 0, stream>>>(qkv, vt);
  k_attn2<<<1024, 256, 0, stream>>>(qkv, vt, att);
  k_gemm_bt<true><<<512, 256, 0, stream>>>(att, wot, d_out, 4096, 2048, 2048, 16);
}

// Round 3
// 226.168 us; speedup vs baseline: 1.9452x; 1.2153x over previous
//
#include <hip/hip_runtime.h>
#include <stdint.h>

typedef __attribute__((ext_vector_type(8))) short short8;
typedef __attribute__((ext_vector_type(4))) short short4v;
typedef __attribute__((ext_vector_type(4))) float float4v;
typedef __attribute__((ext_vector_type(16))) float f32x16;
typedef __attribute__((ext_vector_type(4))) int int4v;
typedef __attribute__((ext_vector_type(2))) int int2v;

#define DEV __device__ __forceinline__

DEV ushort f2bf(float f){
  uint32_t u = __float_as_uint(f);
  u = (u + 0x7fffu + ((u >> 16) & 1u)) >> 16;
  return (ushort)u;
}
DEV float bf2f(ushort h){
  uint32_t u = ((uint32_t)h) << 16;
  return __uint_as_float(u);
}

DEV void gload16(const void* g, void* l){
  __builtin_amdgcn_global_load_lds((const __attribute__((address_space(1))) void*)g,
                                   (__attribute__((address_space(3))) void*)l, 16, 0, 0);
}

DEV uint32_t cvtpk(float lo, float hi){
  uint32_t d;
  asm("v_cvt_pk_bf16_f32 %0, %1, %2" : "=v"(d) : "v"(lo), "v"(hi));
  return d;
}

// ---------------- RoPE cos/sin table: [2048][32] each ----------------
__global__ __launch_bounds__(256) void k_rope_table(float* __restrict__ cost, float* __restrict__ sint){
  int i = blockIdx.x * 256 + threadIdx.x;          // 65536
  int s = i >> 5, d = i & 31;
  float inv = powf(10000.0f, -(float)d / 32.0f);
  float ang = (float)s * inv;
  float sv, cv;
  sincosf(ang, &sv, &cv);
  cost[i] = cv;
  sint[i] = sv;
}

// ---------------- cast x f32 -> bf16 ----------------
__global__ __launch_bounds__(256) void k_cast_x(const float* __restrict__ src, ushort* __restrict__ dst){
  int i = blockIdx.x * 256 + threadIdx.x;          // 2097152 threads, 4 elems each
  float4v v = *(const float4v*)(src + (size_t)i * 4);
  short4v o;
  o[0] = (short)f2bf(v[0]); o[1] = (short)f2bf(v[1]);
  o[2] = (short)f2bf(v[2]); o[3] = (short)f2bf(v[3]);
  *(short4v*)(dst + (size_t)i * 4) = o;
}

// ---------------- transpose + cast + scale: src f32 [K][N] -> dst bf16 [N][K] ----------------
__global__ __launch_bounds__(256) void k_transpose_cast(const float* __restrict__ src, ushort* __restrict__ dst,
                                                        int N, int K, float scale){
  __shared__ float tile[32][33];
  int c0 = blockIdx.x * 32, r0 = blockIdx.y * 32;
  int tx = threadIdx.x & 31, ty = threadIdx.x >> 5;   // ty 0..7
  #pragma unroll
  for (int i = 0; i < 32; i += 8)
    tile[ty + i][tx] = src[(size_t)(r0 + ty + i) * N + (c0 + tx)];
  __syncthreads();
  #pragma unroll
  for (int i = 0; i < 32; i += 8)
    dst[(size_t)(c0 + ty + i) * K + (r0 + tx)] = f2bf(tile[tx][ty + i] * scale);
}

// ---------------- GEMM: C[M][N] = A[M][K] * Bt[N][K]^T, bf16 in, bf16/f32 out ----------------
template<bool OUTF32>
__global__ __launch_bounds__(256) void k_gemm_bt(const ushort* __restrict__ A, const ushort* __restrict__ Bt,
                                                 void* __restrict__ Cp, int M, int N, int K, int nbx){
  __shared__ ushort As[128 * 32];
  __shared__ ushort Bs[128 * 32];
  int wg = blockIdx.x;
  int cpx = (int)gridDim.x >> 3;                 // grid divisible by 8
  wg = (wg & 7) * cpx + (wg >> 3);               // XCD swizzle
  int bn = wg % nbx, bm = wg / nbx;
  const int tid = threadIdx.x;
  const int w = tid >> 6, l = tid & 63, l15 = l & 15, hi = l >> 4;
  const int wr = w >> 1, wc = w & 1;
  float4v acc[4][4];
  #pragma unroll
  for (int a = 0; a < 4; ++a)
    #pragma unroll
    for (int b = 0; b < 4; ++b)
      acc[a][b] = (float4v){0.f, 0.f, 0.f, 0.f};
  const int nk = K >> 5;
  const size_t arow0 = (size_t)(bm * 128) * K;
  const size_t brow0 = (size_t)(bn * 128) * K;
  for (int kt = 0; kt < nk; ++kt){
    __syncthreads();
    #pragma unroll
    for (int r = 0; r < 2; ++r){
      int li = r * 256 + tid;                    // 0..511
      int row = li >> 2, col8 = (li & 3) * 8;
      gload16(A + arow0 + (size_t)row * K + kt * 32 + col8, (char*)As + li * 16);
      gload16(Bt + brow0 + (size_t)row * K + kt * 32 + col8, (char*)Bs + li * 16);
    }
    __syncthreads();
    short8 af[4], bfr[4];
    #pragma unroll
    for (int mf = 0; mf < 4; ++mf)
      af[mf] = *(const short8*)((const char*)As + (wr * 64 + mf * 16 + l15) * 64 + hi * 16);
    #pragma unroll
    for (int nf = 0; nf < 4; ++nf)
      bfr[nf] = *(const short8*)((const char*)Bs + (wc * 64 + nf * 16 + l15) * 64 + hi * 16);
    #pragma unroll
    for (int mf = 0; mf < 4; ++mf)
      #pragma unroll
      for (int nf = 0; nf < 4; ++nf)
        acc[mf][nf] = __builtin_amdgcn_mfma_f32_16x16x32_bf16(af[mf], bfr[nf], acc[mf][nf], 0, 0, 0);
  }
  #pragma unroll
  for (int mf = 0; mf < 4; ++mf){
    int row0 = bm * 128 + wr * 64 + mf * 16 + hi * 4;
    #pragma unroll
    for (int nf = 0; nf < 4; ++nf){
      int col = bn * 128 + wc * 64 + nf * 16 + l15;
      #pragma unroll
      for (int reg = 0; reg < 4; ++reg){
        size_t idx = (size_t)(row0 + reg) * N + col;
        if constexpr (OUTF32) ((float*)Cp)[idx] = acc[mf][nf][reg];
        else                  ((ushort*)Cp)[idx] = f2bf(acc[mf][nf][reg]);
      }
    }
  }
}

// ---------------- RoPE in-place on qkv (q cols [0,2048), k cols [2048,2560)) ----------------
__global__ __launch_bounds__(256) void k_rope(ushort* __restrict__ qkv, const float* __restrict__ cost,
                                              const float* __restrict__ sint){
  int t = blockIdx.x * 256 + threadIdx.x;        // 4096 * 320 = 1310720
  int row = t / 320;
  int rem = t - row * 320;
  int head = rem >> 3, d0 = (rem & 7) * 4;       // head 0..39 covers q(0..31) + k(32..39)
  int s = row & 2047;
  ushort* p = qkv + (size_t)row * 3072 + head * 64 + d0;
  short4v a = *(short4v*)p;
  short4v b = *(short4v*)(p + 32);
  float4v c  = *(const float4v*)(cost + s * 32 + d0);
  float4v sn = *(const float4v*)(sint + s * 32 + d0);
  short4v na, nb;
  #pragma unroll
  for (int j = 0; j < 4; ++j){
    float x1 = bf2f((ushort)a[j]), x2 = bf2f((ushort)b[j]);
    na[j] = (short)f2bf(x1 * c[j] - x2 * sn[j]);
    nb[j] = (short)f2bf(x2 * c[j] + x1 * sn[j]);
  }
  *(short4v*)p = na;
  *(short4v*)(p + 32) = nb;
}

// ---------------- build Vt[b][hk][64 d][2048 s] from qkv v-cols ----------------
__global__ __launch_bounds__(256) void k_build_vt(const ushort* __restrict__ qkv, ushort* __restrict__ vt){
  __shared__ ushort tile[64][72];
  int g = blockIdx.x >> 5, st = blockIdx.x & 31;   // g = b*8+hk, st = s-tile
  int b = g >> 3, hk = g & 7;
  const ushort* src = qkv + (size_t)(b * 2048 + st * 64) * 3072 + 2560 + hk * 64;
  int tid = threadIdx.x;
  #pragma unroll
  for (int i = 0; i < 2; ++i){
    int r = i * 32 + (tid >> 3), c8 = (tid & 7) * 8;
    short8 v = *(const short8*)(src + (size_t)r * 3072 + c8);
    #pragma unroll
    for (int j = 0; j < 8; ++j) tile[r][c8 + j] = (ushort)v[j];
  }
  __syncthreads();
  ushort* dst = vt + (size_t)g * 64 * 2048 + st * 64;
  #pragma unroll
  for (int i = 0; i < 2; ++i){
    int d = i * 32 + (tid >> 3), s8 = (tid & 7) * 8;
    short8 ov;
    #pragma unroll
    for (int j = 0; j < 8; ++j) ov[j] = (short)tile[s8 + j][d];
    *(short8*)(dst + (size_t)d * 2048 + s8) = ov;
  }
}

// ---------------- causal GQA flash attention v3: swapped-operand 32x32 ----------------
// 4 waves x 32 q rows. S^T = mfma32(K, Q^T): lane (q=l&31) owns a full P-row ->
// in-register softmax (lane-local max/l/rescale, defer-max). P->bf16 via cvt_pk +
// 8 shfl_xor(32) half-exchanges -> PV B-frags in registers. O^T = mfma32(Vt, P^T)
// keeps rescale lane-local. No P_lds. K/Vt double-buffered + swizzled in LDS.
__global__ __launch_bounds__(256) void k_attn3(const ushort* __restrict__ qkv, const ushort* __restrict__ vt,
                                               ushort* __restrict__ att){
  __shared__ ushort K_lds[2][64 * 64];
  __shared__ ushort V_lds[2][64 * 64];
  const int raw = blockIdx.x;                     // 1024
  const int xcd = raw & 7, slot = raw >> 3;       // slot 0..127
  const int qb = 15 - (slot >> 3);                // heavy tiles dispatch first
  const int rem = slot & 7;
  const int gidx = xcd * 2 + (rem >> 2);          // b*8+hk : 2 KV-groups per XCD
  const int b = gidx >> 3, hk = gidx & 7;
  const int h = hk * 4 + (rem & 3);
  const int tid = threadIdx.x;
  const int w = tid >> 6, l = tid & 63, ql = l & 31, g = l >> 5;
  const int qw = qb * 128 + w * 32;               // wave's first q row
  const int diag_t = (qw + 31) >> 6;              // last active tile == diagonal tile
  const int swz = (ql & 7) << 4;                  // lane-const LDS read swizzle

  // Q fragments: lane ql's q-row, d-slices of 16 (halves by g)
  short8 qf[4];
  {
    const ushort* qbase = qkv + (size_t)(b * 2048 + qw + ql) * 3072 + h * 64 + g * 8;
    #pragma unroll
    for (int ds = 0; ds < 4; ++ds) qf[ds] = *(const short8*)(qbase + ds * 16);
  }

  f32x16 o0, o1;                                  // O^T acc: d-subtiles 0,1
  #pragma unroll
  for (int r = 0; r < 16; ++r){ o0[r] = 0.f; o1[r] = 0.f; }
  float m_run = -3e38f, l_part = 0.f;

  const ushort* kbase = qkv + (size_t)(b * 2048) * 3072 + 2048 + hk * 64;
  const ushort* vbase = vt + (size_t)gidx * 64 * 2048;
  const int nt = qb * 2 + 2;
  const int srow = tid >> 3, scol = (tid & 7) * 8;   // staging chunk: rows srow, srow+32
  const int swrsw = (srow & 7) << 4;                 // staging write swizzle (rows r, r+32 share)

  // prologue: stage tile 0 into buf 0
  #pragma unroll
  for (int i = 0; i < 2; ++i){
    int r = i * 32 + srow;
    short8 kv = *(const short8*)(kbase + (size_t)r * 3072 + scol);
    short8 vv = *(const short8*)(vbase + (size_t)r * 2048 + scol);
    *(short8*)((char*)K_lds[0] + r * 128 + ((scol * 2) ^ swrsw)) = kv;
    *(short8*)((char*)V_lds[0] + r * 128 + ((scol * 2) ^ swrsw)) = vv;
  }
  __syncthreads();

  int cur = 0;
  for (int t = 0; t < nt; ++t){
    // issue next-tile global loads early
    short8 kpre[2], vpre[2];
    const bool more = (t + 1 < nt);
    if (more){
      const ushort* kb = kbase + (size_t)(t + 1) * 64 * 3072;
      const ushort* vb = vbase + (t + 1) * 64;
      #pragma unroll
      for (int i = 0; i < 2; ++i){
        int r = i * 32 + srow;
        kpre[i] = *(const short8*)(kb + (size_t)r * 3072 + scol);
        vpre[i] = *(const short8*)(vb + (size_t)r * 2048 + scol);
      }
    }

    if (t <= diag_t){
      // ---- QK^T -> S^T (2 k-subtiles x 16 regs per lane) ----
      f32x16 sa0, sa1;
      #pragma unroll
      for (int r = 0; r < 16; ++r){ sa0[r] = 0.f; sa1[r] = 0.f; }
      __builtin_amdgcn_s_setprio(1);
      #pragma unroll
      for (int ds = 0; ds < 4; ++ds){
        int cb = (ds * 32 + g * 16) ^ swz;
        short8 k0 = *(const short8*)((const char*)K_lds[cur] + ql * 128 + cb);
        short8 k1 = *(const short8*)((const char*)K_lds[cur] + (32 + ql) * 128 + cb);
        sa0 = __builtin_amdgcn_mfma_f32_32x32x16_bf16(k0, qf[ds], sa0, 0, 0, 0);
        sa1 = __builtin_amdgcn_mfma_f32_32x32x16_bf16(k1, qf[ds], sa1, 0, 0, 0);
      }
      __builtin_amdgcn_s_setprio(0);

      // ---- causal mask (diagonal tile only) ----
      if (t == diag_t){
        int thr = qw + ql - t * 64;               // keep iff k_local <= thr
        #pragma unroll
        for (int r = 0; r < 16; ++r){
          int kl = (r & 3) + 8 * (r >> 2) + 4 * g;
          sa0[r] = (kl > thr) ? -3e38f : sa0[r];
          sa1[r] = (kl + 32 > thr) ? -3e38f : sa1[r];
        }
      }

      // ---- lane-local max + cross-half merge ----
      float mt = fmaxf(sa0[0], sa1[0]);
      #pragma unroll
      for (int r = 1; r < 16; ++r) mt = fmaxf(mt, fmaxf(sa0[r], sa1[r]));
      mt = fmaxf(mt, __shfl_xor(mt, 32, 64));

      // ---- defer-max rescale (T13) ----
      if (__any(mt > m_run + 8.0f)){
        float mn = fmaxf(m_run, mt);
        float corr = __builtin_amdgcn_exp2f(m_run - mn);
        #pragma unroll
        for (int r = 0; r < 16; ++r){ o0[r] *= corr; o1[r] *= corr; }
        l_part *= corr;
        m_run = mn;
      }

      // ---- exp (base-2; scale folded into Wq) + sum + pack to bf16 words ----
      uint32_t wds[2][8];
      float ps0 = 0.f, ps1 = 0.f, ps2 = 0.f, ps3 = 0.f;
      #pragma unroll
      for (int r = 0; r < 16; ++r){
        float p0 = __builtin_amdgcn_exp2f(sa0[r] - m_run);
        float p1 = __builtin_amdgcn_exp2f(sa1[r] - m_run);
        sa0[r] = p0; sa1[r] = p1;
        if ((r & 3) == 0){ ps0 += p0; ps1 += p1; }
        else if ((r & 3) == 1){ ps2 += p0; ps3 += p1; }
        else if ((r & 3) == 2){ ps0 += p0; ps1 += p1; }
        else { ps2 += p0; ps3 += p1; }
      }
      l_part += (ps0 + ps1) + (ps2 + ps3);
      #pragma unroll
      for (int u = 0; u < 8; ++u){
        wds[0][u] = cvtpk(sa0[2 * u], sa0[2 * u + 1]);
        wds[1][u] = cvtpk(sa1[2 * u], sa1[2 * u + 1]);
      }

      // ---- build P^T B-frags via half-exchange, PV: O^T += Vt * P^T ----
      __builtin_amdgcn_s_setprio(1);
      #pragma unroll
      for (int ks = 0; ks < 4; ++ks){
        const int s2 = ks >> 1, c4 = (ks & 1) * 4;
        uint32_t a0 = wds[s2][c4 + 0], a1 = wds[s2][c4 + 1];
        uint32_t b0 = wds[s2][c4 + 2], b1 = wds[s2][c4 + 3];
        uint32_t s0 = g ? a0 : b0, s1 = g ? a1 : b1;
        uint32_t r0 = (uint32_t)__shfl_xor((int)s0, 32, 64);
        uint32_t r1 = (uint32_t)__shfl_xor((int)s1, 32, 64);
        union { int4v w4; short8 s8; } pb;
        pb.w4[0] = g ? (int)r0 : (int)a0;
        pb.w4[1] = g ? (int)r1 : (int)a1;
        pb.w4[2] = g ? (int)b0 : (int)r0;
        pb.w4[3] = g ? (int)b1 : (int)r1;
        int cb = (ks * 32 + g * 16) ^ swz;
        short8 v0 = *(const short8*)((const char*)V_lds[cur] + ql * 128 + cb);
        short8 v1 = *(const short8*)((const char*)V_lds[cur] + (32 + ql) * 128 + cb);
        o0 = __builtin_amdgcn_mfma_f32_32x32x16_bf16(v0, pb.s8, o0, 0, 0, 0);
        o1 = __builtin_amdgcn_mfma_f32_32x32x16_bf16(v1, pb.s8, o1, 0, 0, 0);
      }
      __builtin_amdgcn_s_setprio(0);
    }

    if (more){
      int nxt = cur ^ 1;
      #pragma unroll
      for (int i = 0; i < 2; ++i){
        int r = i * 32 + srow;
        *(short8*)((char*)K_lds[nxt] + r * 128 + ((scol * 2) ^ swrsw)) = kpre[i];
        *(short8*)((char*)V_lds[nxt] + r * 128 + ((scol * 2) ^ swrsw)) = vpre[i];
      }
      __syncthreads();
      cur = nxt;
    }
  }

  // ---- epilogue: merge l halves, normalize, store O^T (lane = one q-row) ----
  float lf = l_part + __shfl_xor(l_part, 32, 64);
  float invl = 1.0f / lf;
  ushort* ob = att + (size_t)(b * 2048 + qw + ql) * 2048 + h * 64;
  #pragma unroll
  for (int dm = 0; dm < 2; ++dm){
    #pragma unroll
    for (int rg = 0; rg < 4; ++rg){
      float f0 = (dm ? o1[4 * rg + 0] : o0[4 * rg + 0]) * invl;
      float f1 = (dm ? o1[4 * rg + 1] : o0[4 * rg + 1]) * invl;
      float f2 = (dm ? o1[4 * rg + 2] : o0[4 * rg + 2]) * invl;
      float f3 = (dm ? o1[4 * rg + 3] : o0[4 * rg + 3]) * invl;
      int2v wv;
      wv[0] = (int)cvtpk(f0, f1);
      wv[1] = (int)cvtpk(f2, f3);
      int d0 = dm * 32 + 8 * rg + 4 * g;
      *(int2v*)(ob + d0) = wv;
    }
  }
}

// ---------------- launch ----------------
extern "C" void kernel_launch(void* const* d_in, const int* in_sizes, int n_in,
                              void* d_out, int out_size, void* d_ws, size_t ws_size,
                              hipStream_t stream) {
  const float* x  = (const float*)d_in[0];
  // d_in[1] = mask (causal tril; handled analytically)
  const float* Wq = (const float*)d_in[2];
  const float* Wk = (const float*)d_in[3];
  const float* Wv = (const float*)d_in[4];
  const float* Wo = (const float*)d_in[5];

  char* ws = (char*)d_ws;
  ushort* xb    = (ushort*)(ws);                       // [4096][2048] bf16    16 MiB
  ushort* wqkvt = (ushort*)(ws + (16u << 20));         // [3072][2048] bf16    12 MiB
  ushort* wot   = (ushort*)(ws + (28u << 20));         // [2048][2048] bf16     8 MiB
  ushort* qkv   = (ushort*)(ws + (36u << 20));         // [4096][3072] bf16    24 MiB
  ushort* att   = (ushort*)(ws + (60u << 20));         // [4096][2048] bf16    16 MiB
  ushort* vt    = (ushort*)(ws + (76u << 20));         // [16][64][2048] bf16   4 MiB
  float*  cost  = (float*)(ws + (80u << 20));          // [2048][32] f32
  float*  sint  = (float*)(ws + (80u << 20) + 262144);

  const float qscale = 0.125f * 1.4426950408889634f;   // HD^-0.5 * log2(e), folded into Wq

  k_rope_table<<<256, 256, 0, stream>>>(cost, sint);
  k_cast_x<<<8192, 256, 0, stream>>>(x, xb);
  k_transpose_cast<<<dim3(64, 64), 256, 0, stream>>>(Wq, wqkvt, 2048, 2048, qscale);
  k_transpose_cast<<<dim3(16, 64), 256, 0, stream>>>(Wk, wqkvt + (size_t)2048 * 2048, 512, 2048, 1.0f);
  k_transpose_cast<<<dim3(16, 64), 256, 0, stream>>>(Wv, wqkvt + (size_t)2560 * 2048, 512, 2048, 1.0f);
  k_transpose_cast<<<dim3(64, 64), 256, 0, stream>>>(Wo, wot, 2048, 2048, 1.0f);
  k_gemm_bt<false><<<768, 256, 0, stream>>>(xb, wqkvt, qkv, 4096, 3072, 2048, 24);
  k_rope<<<5120, 256, 0, stream>>>(qkv, cost, sint);
  k_build_vt<<<512, 256, 0, stream>>>(qkv, vt);
  k_attn3<<<1024, 256, 0, stream>>>(qkv, vt, att);
  k_gemm_bt<true><<<512, 256, 0, stream>>>(att, wot, d_out, 4096, 2048, 2048, 16);
}

// Round 4
// 210.379 us; speedup vs baseline: 2.0912x; 1.0751x over previous
//
#include <hip/hip_runtime.h>
#include <stdint.h>

typedef __attribute__((ext_vector_type(8))) short short8;
typedef __attribute__((ext_vector_type(4))) short short4v;
typedef __attribute__((ext_vector_type(4))) float float4v;
typedef __attribute__((ext_vector_type(16))) float f32x16;
typedef __attribute__((ext_vector_type(4))) int int4v;
typedef __attribute__((ext_vector_type(2))) int int2v;

#define DEV __device__ __forceinline__

DEV ushort f2bf(float f){
  uint32_t u = __float_as_uint(f);
  u = (u + 0x7fffu + ((u >> 16) & 1u)) >> 16;
  return (ushort)u;
}
DEV float bf2f(ushort h){
  uint32_t u = ((uint32_t)h) << 16;
  return __uint_as_float(u);
}

DEV void gload16(const void* g, void* l){
  __builtin_amdgcn_global_load_lds((const __attribute__((address_space(1))) void*)g,
                                   (__attribute__((address_space(3))) void*)l, 16, 0, 0);
}

DEV uint32_t cvtpk(float lo, float hi){
  uint32_t d;
  asm("v_cvt_pk_bf16_f32 %0, %1, %2" : "=v"(d) : "v"(lo), "v"(hi));
  return d;
}

// ---------------- RoPE cos/sin table: [2048][32] each ----------------
__global__ __launch_bounds__(256) void k_rope_table(float* __restrict__ cost, float* __restrict__ sint){
  int i = blockIdx.x * 256 + threadIdx.x;          // 65536
  int s = i >> 5, d = i & 31;
  float inv = powf(10000.0f, -(float)d / 32.0f);
  float ang = (float)s * inv;
  float sv, cv;
  sincosf(ang, &sv, &cv);
  cost[i] = cv;
  sint[i] = sv;
}

// ---------------- cast x f32 -> bf16 ----------------
__global__ __launch_bounds__(256) void k_cast_x(const float* __restrict__ src, ushort* __restrict__ dst){
  int i = blockIdx.x * 256 + threadIdx.x;          // 2097152 threads, 4 elems each
  float4v v = *(const float4v*)(src + (size_t)i * 4);
  short4v o;
  o[0] = (short)f2bf(v[0]); o[1] = (short)f2bf(v[1]);
  o[2] = (short)f2bf(v[2]); o[3] = (short)f2bf(v[3]);
  *(short4v*)(dst + (size_t)i * 4) = o;
}

// ---------------- transpose + cast + scale: src f32 [K][N] -> dst bf16 [N][K] ----------------
__global__ __launch_bounds__(256) void k_transpose_cast(const float* __restrict__ src, ushort* __restrict__ dst,
                                                        int N, int K, float scale){
  __shared__ float tile[32][33];
  int c0 = blockIdx.x * 32, r0 = blockIdx.y * 32;
  int tx = threadIdx.x & 31, ty = threadIdx.x >> 5;   // ty 0..7
  #pragma unroll
  for (int i = 0; i < 32; i += 8)
    tile[ty + i][tx] = src[(size_t)(r0 + ty + i) * N + (c0 + tx)];
  __syncthreads();
  #pragma unroll
  for (int i = 0; i < 32; i += 8)
    dst[(size_t)(c0 + ty + i) * K + (r0 + tx)] = f2bf(tile[tx][ty + i] * scale);
}

// ---------------- 8-phase 256-class GEMM: C[M][N] = A[M][K] * Bt[N][K]^T ----------------
// 512 thr / 8 waves (2M x 4N), BK=64, 2 K-tile LDS buffers, global_load_lds staging
// with pre-swizzled global source (linear dest) + XOR-swizzled ds_read (T2),
// counted vmcnt pipeline (T3/T4), setprio around MFMA clusters (T5).
template<int BM, int BN, bool OUTF32>
__global__ __launch_bounds__(512, 2) void k_gemm8(const ushort* __restrict__ A, const ushort* __restrict__ Bt,
                                                  void* __restrict__ Cp, int M, int N, int K, int nbx){
  constexpr int WM = BM / 2, WN = BN / 4;
  constexpr int MR = WM / 16, NR = WN / 16, MP = MR / 4;
  constexpr int AISS = BM / 64, BISS = BN / 64, ISS = AISS + BISS;
  constexpr int BUFB = (BM + BN) * 128;            // bytes per K-tile buffer
  __shared__ char lds[2 * BUFB];

  int wg = blockIdx.x;
  int cpx = (int)gridDim.x >> 3;                   // grid divisible by 8
  wg = (wg & 7) * cpx + (wg >> 3);                 // XCD swizzle
  const int bn = wg % nbx, bm = wg / nbx;
  const int tid = threadIdx.x;
  const int w = tid >> 6, l = tid & 63, l15 = l & 15, hi = l >> 4;
  const int wr = w >> 2, wc = w & 3;

  // staging geometry: thread covers row r8 (+i*64), 16B at swizzle-corrected col
  const int r8 = tid >> 3;
  const int ce = ((tid & 7) ^ (r8 & 7)) << 3;      // pre-swizzled source col element
  const ushort* ag = A + (size_t)(bm * BM + r8) * K + ce;
  const ushort* bg = Bt + (size_t)(bn * BN + r8) * K + ce;

  float4v acc[MR][NR];
  #pragma unroll
  for (int a = 0; a < MR; ++a)
    #pragma unroll
    for (int b = 0; b < NR; ++b)
      acc[a][b] = (float4v){0.f, 0.f, 0.f, 0.f};

  auto stage = [&](int kt, int buf){
    char* ab = lds + buf * BUFB;
    char* bb = ab + BM * 128;
    #pragma unroll
    for (int i = 0; i < AISS; ++i)
      gload16(ag + (size_t)(i * 64) * K + kt * 64, ab + i * 8192 + tid * 16);
    #pragma unroll
    for (int i = 0; i < BISS; ++i)
      gload16(bg + (size_t)(i * 64) * K + kt * 64, bb + i * 8192 + tid * 16);
  };
  auto lda = [&](const char* ab, int mf, int kk)->short8{
    int row = wr * WM + mf * 16 + l15;
    int a = (row * 128 + kk * 64 + hi * 16) ^ ((row & 7) << 4);
    return *(const short8*)(ab + a);
  };
  auto ldb = [&](const char* bb, int nf, int kk)->short8{
    int row = wc * WN + nf * 16 + l15;
    int a = (row * 128 + kk * 64 + hi * 16) ^ ((row & 7) << 4);
    return *(const short8*)(bb + a);
  };

  const int nkt = K >> 6;
  stage(0, 0);
  for (int t = 0; t < nkt; ++t){
    if (t + 1 < nkt){
      stage(t + 1, (t + 1) & 1);
      if constexpr (ISS == 8) asm volatile("s_waitcnt vmcnt(8)" ::: "memory");
      else                    asm volatile("s_waitcnt vmcnt(6)" ::: "memory");
    } else {
      asm volatile("s_waitcnt vmcnt(0)" ::: "memory");
    }
    __builtin_amdgcn_s_barrier();
    __builtin_amdgcn_sched_barrier(0);

    const char* ab = lds + (t & 1) * BUFB;
    const char* bb = ab + BM * 128;
    short8 bfr[NR][2];
    #pragma unroll
    for (int nf = 0; nf < NR; ++nf){ bfr[nf][0] = ldb(bb, nf, 0); bfr[nf][1] = ldb(bb, nf, 1); }
    short8 af[MP][2];
    #pragma unroll
    for (int ml = 0; ml < MP; ++ml){ af[ml][0] = lda(ab, ml, 0); af[ml][1] = lda(ab, ml, 1); }

    #pragma unroll
    for (int p = 0; p < 4; ++p){
      __builtin_amdgcn_s_barrier();
      asm volatile("s_waitcnt lgkmcnt(0)" ::: "memory");
      __builtin_amdgcn_sched_barrier(0);
      __builtin_amdgcn_s_setprio(1);
      #pragma unroll
      for (int ml = 0; ml < MP; ++ml)
        #pragma unroll
        for (int nf = 0; nf < NR; ++nf){
          const int mf = p * MP + ml;
          acc[mf][nf] = __builtin_amdgcn_mfma_f32_16x16x32_bf16(af[ml][0], bfr[nf][0], acc[mf][nf], 0, 0, 0);
          acc[mf][nf] = __builtin_amdgcn_mfma_f32_16x16x32_bf16(af[ml][1], bfr[nf][1], acc[mf][nf], 0, 0, 0);
        }
      __builtin_amdgcn_s_setprio(0);
      __builtin_amdgcn_sched_barrier(0);
      if (p < 3){
        #pragma unroll
        for (int ml = 0; ml < MP; ++ml){
          af[ml][0] = lda(ab, (p + 1) * MP + ml, 0);
          af[ml][1] = lda(ab, (p + 1) * MP + ml, 1);
        }
      }
      __builtin_amdgcn_s_barrier();
    }
  }

  #pragma unroll
  for (int mf = 0; mf < MR; ++mf){
    int row0 = bm * BM + wr * WM + mf * 16 + hi * 4;
    #pragma unroll
    for (int nf = 0; nf < NR; ++nf){
      int col = bn * BN + wc * WN + nf * 16 + l15;
      #pragma unroll
      for (int reg = 0; reg < 4; ++reg){
        size_t idx = (size_t)(row0 + reg) * N + col;
        if constexpr (OUTF32) ((float*)Cp)[idx] = acc[mf][nf][reg];
        else                  ((ushort*)Cp)[idx] = f2bf(acc[mf][nf][reg]);
      }
    }
  }
}

// ---------------- RoPE in-place on qkv (q cols [0,2048), k cols [2048,2560)) ----------------
__global__ __launch_bounds__(256) void k_rope(ushort* __restrict__ qkv, const float* __restrict__ cost,
                                              const float* __restrict__ sint){
  int t = blockIdx.x * 256 + threadIdx.x;        // 4096 * 320 = 1310720
  int row = t / 320;
  int rem = t - row * 320;
  int head = rem >> 3, d0 = (rem & 7) * 4;       // head 0..39 covers q(0..31) + k(32..39)
  int s = row & 2047;
  ushort* p = qkv + (size_t)row * 3072 + head * 64 + d0;
  short4v a = *(short4v*)p;
  short4v b = *(short4v*)(p + 32);
  float4v c  = *(const float4v*)(cost + s * 32 + d0);
  float4v sn = *(const float4v*)(sint + s * 32 + d0);
  short4v na, nb;
  #pragma unroll
  for (int j = 0; j < 4; ++j){
    float x1 = bf2f((ushort)a[j]), x2 = bf2f((ushort)b[j]);
    na[j] = (short)f2bf(x1 * c[j] - x2 * sn[j]);
    nb[j] = (short)f2bf(x2 * c[j] + x1 * sn[j]);
  }
  *(short4v*)p = na;
  *(short4v*)(p + 32) = nb;
}

// ---------------- build Vt[b][hk][64 d][2048 s] from qkv v-cols ----------------
__global__ __launch_bounds__(256) void k_build_vt(const ushort* __restrict__ qkv, ushort* __restrict__ vt){
  __shared__ ushort tile[64][72];
  int g = blockIdx.x >> 5, st = blockIdx.x & 31;   // g = b*8+hk, st = s-tile
  int b = g >> 3, hk = g & 7;
  const ushort* src = qkv + (size_t)(b * 2048 + st * 64) * 3072 + 2560 + hk * 64;
  int tid = threadIdx.x;
  #pragma unroll
  for (int i = 0; i < 2; ++i){
    int r = i * 32 + (tid >> 3), c8 = (tid & 7) * 8;
    short8 v = *(const short8*)(src + (size_t)r * 3072 + c8);
    #pragma unroll
    for (int j = 0; j < 8; ++j) tile[r][c8 + j] = (ushort)v[j];
  }
  __syncthreads();
  ushort* dst = vt + (size_t)g * 64 * 2048 + st * 64;
  #pragma unroll
  for (int i = 0; i < 2; ++i){
    int d = i * 32 + (tid >> 3), s8 = (tid & 7) * 8;
    short8 ov;
    #pragma unroll
    for (int j = 0; j < 8; ++j) ov[j] = (short)tile[s8 + j][d];
    *(short8*)(dst + (size_t)d * 2048 + s8) = ov;
  }
}

// ---------------- causal GQA flash attention v3: swapped-operand 32x32 ----------------
__global__ __launch_bounds__(256) void k_attn3(const ushort* __restrict__ qkv, const ushort* __restrict__ vt,
                                               ushort* __restrict__ att){
  __shared__ ushort K_lds[2][64 * 64];
  __shared__ ushort V_lds[2][64 * 64];
  const int raw = blockIdx.x;                     // 1024
  const int xcd = raw & 7, slot = raw >> 3;       // slot 0..127
  const int qb = 15 - (slot >> 3);                // heavy tiles dispatch first
  const int rem = slot & 7;
  const int gidx = xcd * 2 + (rem >> 2);          // b*8+hk : 2 KV-groups per XCD
  const int b = gidx >> 3, hk = gidx & 7;
  const int h = hk * 4 + (rem & 3);
  const int tid = threadIdx.x;
  const int w = tid >> 6, l = tid & 63, ql = l & 31, g = l >> 5;
  const int qw = qb * 128 + w * 32;               // wave's first q row
  const int diag_t = (qw + 31) >> 6;              // last active tile == diagonal tile
  const int swz = (ql & 7) << 4;                  // lane-const LDS read swizzle

  short8 qf[4];
  {
    const ushort* qbase = qkv + (size_t)(b * 2048 + qw + ql) * 3072 + h * 64 + g * 8;
    #pragma unroll
    for (int ds = 0; ds < 4; ++ds) qf[ds] = *(const short8*)(qbase + ds * 16);
  }

  f32x16 o0, o1;                                  // O^T acc: d-subtiles 0,1
  #pragma unroll
  for (int r = 0; r < 16; ++r){ o0[r] = 0.f; o1[r] = 0.f; }
  float m_run = -3e38f, l_part = 0.f;

  const ushort* kbase = qkv + (size_t)(b * 2048) * 3072 + 2048 + hk * 64;
  const ushort* vbase = vt + (size_t)gidx * 64 * 2048;
  const int nt = qb * 2 + 2;
  const int srow = tid >> 3, scol = (tid & 7) * 8;
  const int swrsw = (srow & 7) << 4;

  #pragma unroll
  for (int i = 0; i < 2; ++i){
    int r = i * 32 + srow;
    short8 kv = *(const short8*)(kbase + (size_t)r * 3072 + scol);
    short8 vv = *(const short8*)(vbase + (size_t)r * 2048 + scol);
    *(short8*)((char*)K_lds[0] + r * 128 + ((scol * 2) ^ swrsw)) = kv;
    *(short8*)((char*)V_lds[0] + r * 128 + ((scol * 2) ^ swrsw)) = vv;
  }
  __syncthreads();

  int cur = 0;
  for (int t = 0; t < nt; ++t){
    short8 kpre[2], vpre[2];
    const bool more = (t + 1 < nt);
    if (more){
      const ushort* kb = kbase + (size_t)(t + 1) * 64 * 3072;
      const ushort* vb = vbase + (t + 1) * 64;
      #pragma unroll
      for (int i = 0; i < 2; ++i){
        int r = i * 32 + srow;
        kpre[i] = *(const short8*)(kb + (size_t)r * 3072 + scol);
        vpre[i] = *(const short8*)(vb + (size_t)r * 2048 + scol);
      }
    }

    if (t <= diag_t){
      f32x16 sa0, sa1;
      #pragma unroll
      for (int r = 0; r < 16; ++r){ sa0[r] = 0.f; sa1[r] = 0.f; }
      __builtin_amdgcn_s_setprio(1);
      #pragma unroll
      for (int ds = 0; ds < 4; ++ds){
        int cb = (ds * 32 + g * 16) ^ swz;
        short8 k0 = *(const short8*)((const char*)K_lds[cur] + ql * 128 + cb);
        short8 k1 = *(const short8*)((const char*)K_lds[cur] + (32 + ql) * 128 + cb);
        sa0 = __builtin_amdgcn_mfma_f32_32x32x16_bf16(k0, qf[ds], sa0, 0, 0, 0);
        sa1 = __builtin_amdgcn_mfma_f32_32x32x16_bf16(k1, qf[ds], sa1, 0, 0, 0);
      }
      __builtin_amdgcn_s_setprio(0);

      if (t == diag_t){
        int thr = qw + ql - t * 64;
        #pragma unroll
        for (int r = 0; r < 16; ++r){
          int kl = (r & 3) + 8 * (r >> 2) + 4 * g;
          sa0[r] = (kl > thr) ? -3e38f : sa0[r];
          sa1[r] = (kl + 32 > thr) ? -3e38f : sa1[r];
        }
      }

      float mt = fmaxf(sa0[0], sa1[0]);
      #pragma unroll
      for (int r = 1; r < 16; ++r) mt = fmaxf(mt, fmaxf(sa0[r], sa1[r]));
      mt = fmaxf(mt, __shfl_xor(mt, 32, 64));

      if (__any(mt > m_run + 8.0f)){
        float mn = fmaxf(m_run, mt);
        float corr = __builtin_amdgcn_exp2f(m_run - mn);
        #pragma unroll
        for (int r = 0; r < 16; ++r){ o0[r] *= corr; o1[r] *= corr; }
        l_part *= corr;
        m_run = mn;
      }

      uint32_t wds[2][8];
      float ps0 = 0.f, ps1 = 0.f, ps2 = 0.f, ps3 = 0.f;
      #pragma unroll
      for (int r = 0; r < 16; ++r){
        float p0 = __builtin_amdgcn_exp2f(sa0[r] - m_run);
        float p1 = __builtin_amdgcn_exp2f(sa1[r] - m_run);
        sa0[r] = p0; sa1[r] = p1;
        if ((r & 1) == 0){ ps0 += p0; ps1 += p1; }
        else { ps2 += p0; ps3 += p1; }
      }
      l_part += (ps0 + ps2) + (ps1 + ps3);
      #pragma unroll
      for (int u = 0; u < 8; ++u){
        wds[0][u] = cvtpk(sa0[2 * u], sa0[2 * u + 1]);
        wds[1][u] = cvtpk(sa1[2 * u], sa1[2 * u + 1]);
      }

      __builtin_amdgcn_s_setprio(1);
      #pragma unroll
      for (int ks = 0; ks < 4; ++ks){
        const int s2 = ks >> 1, c4 = (ks & 1) * 4;
        uint32_t a0 = wds[s2][c4 + 0], a1 = wds[s2][c4 + 1];
        uint32_t b0 = wds[s2][c4 + 2], b1 = wds[s2][c4 + 3];
        uint32_t s0 = g ? a0 : b0, s1 = g ? a1 : b1;
        uint32_t r0 = (uint32_t)__shfl_xor((int)s0, 32, 64);
        uint32_t r1 = (uint32_t)__shfl_xor((int)s1, 32, 64);
        union { int4v w4; short8 s8; } pb;
        pb.w4[0] = g ? (int)r0 : (int)a0;
        pb.w4[1] = g ? (int)r1 : (int)a1;
        pb.w4[2] = g ? (int)b0 : (int)r0;
        pb.w4[3] = g ? (int)b1 : (int)r1;
        int cb = (ks * 32 + g * 16) ^ swz;
        short8 v0 = *(const short8*)((const char*)V_lds[cur] + ql * 128 + cb);
        short8 v1 = *(const short8*)((const char*)V_lds[cur] + (32 + ql) * 128 + cb);
        o0 = __builtin_amdgcn_mfma_f32_32x32x16_bf16(v0, pb.s8, o0, 0, 0, 0);
        o1 = __builtin_amdgcn_mfma_f32_32x32x16_bf16(v1, pb.s8, o1, 0, 0, 0);
      }
      __builtin_amdgcn_s_setprio(0);
    }

    if (more){
      int nxt = cur ^ 1;
      #pragma unroll
      for (int i = 0; i < 2; ++i){
        int r = i * 32 + srow;
        *(short8*)((char*)K_lds[nxt] + r * 128 + ((scol * 2) ^ swrsw)) = kpre[i];
        *(short8*)((char*)V_lds[nxt] + r * 128 + ((scol * 2) ^ swrsw)) = vpre[i];
      }
      __syncthreads();
      cur = nxt;
    }
  }

  float lf = l_part + __shfl_xor(l_part, 32, 64);
  float invl = 1.0f / lf;
  ushort* ob = att + (size_t)(b * 2048 + qw + ql) * 2048 + h * 64;
  #pragma unroll
  for (int dm = 0; dm < 2; ++dm){
    #pragma unroll
    for (int rg = 0; rg < 4; ++rg){
      float f0 = (dm ? o1[4 * rg + 0] : o0[4 * rg + 0]) * invl;
      float f1 = (dm ? o1[4 * rg + 1] : o0[4 * rg + 1]) * invl;
      float f2 = (dm ? o1[4 * rg + 2] : o0[4 * rg + 2]) * invl;
      float f3 = (dm ? o1[4 * rg + 3] : o0[4 * rg + 3]) * invl;
      int2v wv;
      wv[0] = (int)cvtpk(f0, f1);
      wv[1] = (int)cvtpk(f2, f3);
      int d0 = dm * 32 + 8 * rg + 4 * g;
      *(int2v*)(ob + d0) = wv;
    }
  }
}

// ---------------- launch ----------------
extern "C" void kernel_launch(void* const* d_in, const int* in_sizes, int n_in,
                              void* d_out, int out_size, void* d_ws, size_t ws_size,
                              hipStream_t stream) {
  const float* x  = (const float*)d_in[0];
  // d_in[1] = mask (causal tril; handled analytically)
  const float* Wq = (const float*)d_in[2];
  const float* Wk = (const float*)d_in[3];
  const float* Wv = (const float*)d_in[4];
  const float* Wo = (const float*)d_in[5];

  char* ws = (char*)d_ws;
  ushort* xb    = (ushort*)(ws);                       // [4096][2048] bf16    16 MiB
  ushort* wqkvt = (ushort*)(ws + (16u << 20));         // [3072][2048] bf16    12 MiB
  ushort* wot   = (ushort*)(ws + (28u << 20));         // [2048][2048] bf16     8 MiB
  ushort* qkv   = (ushort*)(ws + (36u << 20));         // [4096][3072] bf16    24 MiB
  ushort* att   = (ushort*)(ws + (60u << 20));         // [4096][2048] bf16    16 MiB
  ushort* vt    = (ushort*)(ws + (76u << 20));         // [16][64][2048] bf16   4 MiB
  float*  cost  = (float*)(ws + (80u << 20));          // [2048][32] f32
  float*  sint  = (float*)(ws + (80u << 20) + 262144);

  const float qscale = 0.125f * 1.4426950408889634f;   // HD^-0.5 * log2(e), folded into Wq

  k_rope_table<<<256, 256, 0, stream>>>(cost, sint);
  k_cast_x<<<8192, 256, 0, stream>>>(x, xb);
  k_transpose_cast<<<dim3(64, 64), 256, 0, stream>>>(Wq, wqkvt, 2048, 2048, qscale);
  k_transpose_cast<<<dim3(16, 64), 256, 0, stream>>>(Wk, wqkvt + (size_t)2048 * 2048, 512, 2048, 1.0f);
  k_transpose_cast<<<dim3(16, 64), 256, 0, stream>>>(Wv, wqkvt + (size_t)2560 * 2048, 512, 2048, 1.0f);
  k_transpose_cast<<<dim3(64, 64), 256, 0, stream>>>(Wo, wot, 2048, 2048, 1.0f);
  k_gemm8<256, 256, false><<<192, 512, 0, stream>>>(xb, wqkvt, qkv, 4096, 3072, 2048, 12);
  k_rope<<<5120, 256, 0, stream>>>(qkv, cost, sint);
  k_build_vt<<<512, 256, 0, stream>>>(qkv, vt);
  k_attn3<<<1024, 256, 0, stream>>>(qkv, vt, att);
  k_gemm8<128, 256, true><<<256, 512, 0, stream>>>(att, wot, d_out, 4096, 2048, 2048, 8);
}